// Round 11
// baseline (26.708 us; speedup 1.0000x reference)
//
#include <hip/hip_runtime.h>
#include <hip/hip_bf16.h>

// Problem constants (from reference setup_inputs): emission [B, T, V] float32
#define CTC_B 64
#define CTC_T 8192
#define CTC_V 32
#define BLANK 0

// ---------------------------------------------------------------------------
// MEASUREMENT ROUND 2: identical to R10 (best, 21.18 us) except the compact
// kernel is launched TWICE (idempotent). dur - 21.18 = marginal cost of one
// steady-state compact dispatch (incl. node overhead). Completes the
// decomposition: argmax=10.87 (R9 probe), compact=this, fixed=rest.
// ---------------------------------------------------------------------------

// ---------------------------------------------------------------------------
// Kernel 1: argmax over labels. 4 lanes per (b,t) row; fmaxf tree + equality
// index scan (first-occurrence tie-break identical to jnp.argmax).
// ---------------------------------------------------------------------------
__global__ __launch_bounds__(256) void ctc_argmax_kernel(
    const float* __restrict__ em, unsigned char* __restrict__ idx) {
    int tid = blockIdx.x * blockDim.x + threadIdx.x;   // 4 threads per row
    int row = tid >> 2;
    int sub = tid & 3;
    const float4* p = reinterpret_cast<const float4*>(em) + (size_t)row * 8 + sub;
    float4 a = p[0];   // covers elements 4*sub    .. 4*sub+3
    float4 b = p[4];   // covers elements 16+4*sub .. 16+4*sub+3

    // in-lane max of 8 values: v_max3-friendly tree (4 ops)
    float m0 = __builtin_fmaxf(__builtin_fmaxf(a.x, a.y), a.z);
    float m1 = __builtin_fmaxf(__builtin_fmaxf(a.w, b.x), b.y);
    float m2 = __builtin_fmaxf(b.z, b.w);
    float g  = __builtin_fmaxf(__builtin_fmaxf(m0, m1), m2);

    // group max across the 4-lane group (xor masks 1,2 stay in-group)
    g = __builtin_fmaxf(g, __shfl_xor(g, 1, 64));
    g = __builtin_fmaxf(g, __shfl_xor(g, 2, 64));

    // local first-match index in global element order (descending scan ->
    // earliest e wins); sentinel 255 if this lane has no match.
    const int e1 = sub * 4, e2 = 16 + sub * 4;
    int li = 255;
    if (b.w == g) li = e2 + 3;
    if (b.z == g) li = e2 + 2;
    if (b.y == g) li = e2 + 1;
    if (b.x == g) li = e2;
    if (a.w == g) li = e1 + 3;
    if (a.z == g) li = e1 + 2;
    if (a.y == g) li = e1 + 1;
    if (a.x == g) li = e1;

    // group min-index (at least one lane has a match)
    li = min(li, __shfl_xor(li, 1, 64));
    li = min(li, __shfl_xor(li, 2, 64));

    if (sub == 0) idx[row] = (unsigned char)li;   // 16 consecutive bytes/wave
}

// ---------------------------------------------------------------------------
// SWAR: high bit of each byte set iff that byte of x is nonzero.
// ---------------------------------------------------------------------------
__device__ __forceinline__ unsigned long long nzmask(unsigned long long x) {
    return (x | ((x & 0x7f7f7f7f7f7f7f7fULL) + 0x7f7f7f7f7f7f7f7fULL))
           & 0x8080808080808080ULL;
}

// ---------------------------------------------------------------------------
// Kernel 2 (fused colkeep + compact): one block of 1024 threads per batch
// row; each thread owns 8 CONSECUTIVE columns (one u64 byte-vector). Single
// pass, single barrier. (Unchanged from the 21.18 us best.)
// ---------------------------------------------------------------------------
__global__ __launch_bounds__(1024) void ctc_compact_kernel(
    const unsigned char* __restrict__ idx,
    int* __restrict__ btokens, int* __restrict__ lens) {
    const int b   = blockIdx.x;
    const int tid = threadIdx.x;
    const int t8  = tid * 8;                     // first column this thread owns
    const unsigned char* row = idx + (size_t)b * CTC_T;
    int* orow = btokens + (size_t)b * CTC_T;

    __shared__ int s_wsum[16];
    const int lane = tid & 63;
    const int wid  = tid >> 6;

    // --- load own 8 values + boundary byte, and dedup rows 0,1 ---
    const unsigned long long xv = *reinterpret_cast<const unsigned long long*>(row + t8);
    const unsigned char* r0 = idx;               // batch row 0
    const unsigned char* r1 = idx + CTC_T;       // batch row 1
    unsigned long long x0 = *reinterpret_cast<const unsigned long long*>(r0 + t8);
    unsigned long long x1 = *reinterpret_cast<const unsigned long long*>(r1 + t8);
    unsigned char p0 = (t8 == 0) ? (unsigned char)0 : r0[t8 - 1];
    unsigned char p1 = (t8 == 0) ? (unsigned char)0 : r1[t8 - 1];

    // colkeep high-bit mask: byte j <-> column t8+j ; prev column = byte j-1
    unsigned long long hk = nzmask(x0 ^ ((x0 << 8) | (unsigned long long)p0))
                          | nzmask(x1 ^ ((x1 << 8) | (unsigned long long)p1));
    if (t8 == 0) hk |= 0x80ULL;                  // col_keep[0] = 1 always

    unsigned long long und = ~hk & 0x8080808080808080ULL;
    for (int bb = 2; bb < CTC_B && und; ++bb) {
        const unsigned char* rb = idx + (size_t)bb * CTC_T;
        unsigned long long xb = *reinterpret_cast<const unsigned long long*>(rb + t8);
        unsigned char pb = (t8 == 0) ? (unsigned char)0 : rb[t8 - 1];
        hk |= nzmask(xb ^ ((xb << 8) | (unsigned long long)pb));
        und = ~hk & 0x8080808080808080ULL;
    }

    // keep = col_keep & (value != BLANK)   (BLANK==0 -> nonzero byte)
    const unsigned long long keep_hi = hk & nzmask(xv);
    const int c = __popcll(keep_hi);

    // --- block exclusive scan of per-thread counts ---
    int scan = c;
#pragma unroll
    for (int m = 1; m < 64; m <<= 1) {
        int o = __shfl_up(scan, m, 64);
        if (lane >= m) scan += o;
    }
    if (lane == 63) s_wsum[wid] = scan;          // wave total (inclusive of last)
    __syncthreads();

    int woff = 0, total = 0;
#pragma unroll
    for (int w = 0; w < 16; ++w) {
        int x = s_wsum[w];
        if (w < wid) woff += x;
        total += x;
    }
    int pos = woff + (scan - c);                 // global exclusive prefix

    // --- scatter kept tokens (consecutive per thread) ---
#pragma unroll
    for (int j = 0; j < 8; ++j) {
        if (keep_hi & (0x80ULL << (8 * j))) {
            orow[pos++] = (int)((xv >> (8 * j)) & 0xffULL);
        }
    }

    // --- tail zero-fill (int4-vectorized) + lens ---
    int vstart = (total + 3) & ~3;               // 16B-aligned fill start
    if (tid < vstart - total) orow[total + tid] = BLANK;
    int4* vout = reinterpret_cast<int4*>(orow + vstart);
    const int nvec = (CTC_T - vstart) >> 2;
    const int4 z = make_int4(BLANK, BLANK, BLANK, BLANK);
    for (int i = tid; i < nvec; i += 1024) vout[i] = z;
    if (tid == 0) lens[b] = total;
}

// ---------------------------------------------------------------------------
extern "C" void kernel_launch(void* const* d_in, const int* in_sizes, int n_in,
                              void* d_out, int out_size, void* d_ws, size_t ws_size,
                              hipStream_t stream) {
    const float* emission = (const float*)d_in[0];
    int* out = (int*)d_out;                 // [B*T btokens][B lens], int32
    int* btokens = out;
    int* lens = out + (size_t)CTC_B * CTC_T;

    unsigned char* idx = (unsigned char*)d_ws;   // B*T bytes

    const int total_threads = CTC_B * CTC_T * 4; // 4 lanes per row
    ctc_argmax_kernel<<<total_threads / 256, 256, 0, stream>>>(emission, idx);
    // PROBE: compact launched twice (idempotent). Marginal dur = t_compact.
    ctc_compact_kernel<<<CTC_B, 1024, 0, stream>>>(idx, btokens, lens);
    ctc_compact_kernel<<<CTC_B, 1024, 0, stream>>>(idx, btokens, lens);
}

// Round 12
// 20.205 us; speedup vs baseline: 1.3219x; 1.3219x over previous
//
#include <hip/hip_runtime.h>
#include <hip/hip_bf16.h>

// Problem constants (from reference setup_inputs): emission [B, T, V] float32
#define CTC_B 64
#define CTC_T 8192
#define CTC_V 32
#define BLANK 0

#define SEGS 4
#define SEGW (CTC_T / SEGS)   // 2048 columns per segment

// ---------------------------------------------------------------------------
// Kernel 1: argmax over labels. 4 lanes per (b,t) row; fmaxf tree + equality
// index scan (first-occurrence tie-break identical to jnp.argmax).
// Measured at 10.87 us marginal = 98% of the 6.3 TB/s read ceiling (R9).
// ---------------------------------------------------------------------------
__global__ __launch_bounds__(256) void ctc_argmax_kernel(
    const float* __restrict__ em, unsigned char* __restrict__ idx) {
    int tid = blockIdx.x * blockDim.x + threadIdx.x;   // 4 threads per row
    int row = tid >> 2;
    int sub = tid & 3;
    const float4* p = reinterpret_cast<const float4*>(em) + (size_t)row * 8 + sub;
    float4 a = p[0];   // covers elements 4*sub    .. 4*sub+3
    float4 b = p[4];   // covers elements 16+4*sub .. 16+4*sub+3

    // in-lane max of 8 values: v_max3-friendly tree (4 ops)
    float m0 = __builtin_fmaxf(__builtin_fmaxf(a.x, a.y), a.z);
    float m1 = __builtin_fmaxf(__builtin_fmaxf(a.w, b.x), b.y);
    float m2 = __builtin_fmaxf(b.z, b.w);
    float g  = __builtin_fmaxf(__builtin_fmaxf(m0, m1), m2);

    // group max across the 4-lane group (xor masks 1,2 stay in-group)
    g = __builtin_fmaxf(g, __shfl_xor(g, 1, 64));
    g = __builtin_fmaxf(g, __shfl_xor(g, 2, 64));

    // local first-match index in global element order (descending scan ->
    // earliest e wins); sentinel 255 if this lane has no match.
    const int e1 = sub * 4, e2 = 16 + sub * 4;
    int li = 255;
    if (b.w == g) li = e2 + 3;
    if (b.z == g) li = e2 + 2;
    if (b.y == g) li = e2 + 1;
    if (b.x == g) li = e2;
    if (a.w == g) li = e1 + 3;
    if (a.z == g) li = e1 + 2;
    if (a.y == g) li = e1 + 1;
    if (a.x == g) li = e1;

    // group min-index (at least one lane has a match)
    li = min(li, __shfl_xor(li, 1, 64));
    li = min(li, __shfl_xor(li, 2, 64));

    if (sub == 0) idx[row] = (unsigned char)li;   // 16 consecutive bytes/wave
}

// ---------------------------------------------------------------------------
// SWAR: high bit of each byte set iff that byte of x is nonzero.
// ---------------------------------------------------------------------------
__device__ __forceinline__ unsigned long long nzmask(unsigned long long x) {
    return (x | ((x & 0x7f7f7f7f7f7f7f7fULL) + 0x7f7f7f7f7f7f7f7fULL))
           & 0x8080808080808080ULL;
}

// ---------------------------------------------------------------------------
// Kernel 2 (fused colkeep + compact), R12: 4-WAY ROW-SPLIT, 256 blocks.
// Block (b,s) = blockIdx (b = blk & 63, s = blk >> 6):
//   - ALL 1024 threads compute the full row-b keep-mask + block scan
//     (redundant across the 4 blocks of row b — deterministic & cheap);
//   - only threads [256s, 256s+256) scatter their kept tokens;
//   - block fills only output range [2048s, 2048(s+1)) ∩ [total, T) of tail;
//   - lens[b] written by s==0.
// No cross-block communication; 4x CU coverage vs the 64-block version.
// ---------------------------------------------------------------------------
__global__ __launch_bounds__(1024) void ctc_compact_kernel(
    const unsigned char* __restrict__ idx,
    int* __restrict__ btokens, int* __restrict__ lens) {
    const int blk = blockIdx.x;
    const int b   = blk & 63;
    const int s   = blk >> 6;
    const int tid = threadIdx.x;
    const int t8  = tid * 8;                     // first column this thread owns
    const unsigned char* row = idx + (size_t)b * CTC_T;
    int* orow = btokens + (size_t)b * CTC_T;

    __shared__ int s_wsum[16];
    const int lane = tid & 63;
    const int wid  = tid >> 6;

    // --- load own 8 values + boundary byte, and dedup rows 0,1 ---
    const unsigned long long xv = *reinterpret_cast<const unsigned long long*>(row + t8);
    const unsigned char* r0 = idx;               // batch row 0
    const unsigned char* r1 = idx + CTC_T;       // batch row 1
    unsigned long long x0 = *reinterpret_cast<const unsigned long long*>(r0 + t8);
    unsigned long long x1 = *reinterpret_cast<const unsigned long long*>(r1 + t8);
    unsigned char p0 = (t8 == 0) ? (unsigned char)0 : r0[t8 - 1];
    unsigned char p1 = (t8 == 0) ? (unsigned char)0 : r1[t8 - 1];

    // colkeep high-bit mask: byte j <-> column t8+j ; prev column = byte j-1
    unsigned long long hk = nzmask(x0 ^ ((x0 << 8) | (unsigned long long)p0))
                          | nzmask(x1 ^ ((x1 << 8) | (unsigned long long)p1));
    if (t8 == 0) hk |= 0x80ULL;                  // col_keep[0] = 1 always

    unsigned long long und = ~hk & 0x8080808080808080ULL;
    for (int bb = 2; bb < CTC_B && und; ++bb) {
        const unsigned char* rb = idx + (size_t)bb * CTC_T;
        unsigned long long xb = *reinterpret_cast<const unsigned long long*>(rb + t8);
        unsigned char pb = (t8 == 0) ? (unsigned char)0 : rb[t8 - 1];
        hk |= nzmask(xb ^ ((xb << 8) | (unsigned long long)pb));
        und = ~hk & 0x8080808080808080ULL;
    }

    // keep = col_keep & (value != BLANK)   (BLANK==0 -> nonzero byte)
    const unsigned long long keep_hi = hk & nzmask(xv);
    const int c = __popcll(keep_hi);

    // --- block exclusive scan of per-thread counts (identical in all 4
    //     blocks of row b) ---
    int scan = c;
#pragma unroll
    for (int m = 1; m < 64; m <<= 1) {
        int o = __shfl_up(scan, m, 64);
        if (lane >= m) scan += o;
    }
    if (lane == 63) s_wsum[wid] = scan;          // wave total (inclusive of last)
    __syncthreads();

    int woff = 0, total = 0;
#pragma unroll
    for (int w = 0; w < 16; ++w) {
        int x = s_wsum[w];
        if (w < wid) woff += x;
        total += x;
    }
    int pos = woff + (scan - c);                 // global exclusive prefix

    // --- scatter kept tokens: only this block's segment of input columns ---
    if ((tid >> 8) == s) {
#pragma unroll
        for (int j = 0; j < 8; ++j) {
            if (keep_hi & (0x80ULL << (8 * j))) {
                orow[pos++] = (int)((xv >> (8 * j)) & 0xffULL);
            }
        }
    }

    // --- tail zero-fill of this block's OUTPUT quarter + lens ---
    const int fe = SEGW * (s + 1);               // fill end (exclusive)
    int fs = total > SEGW * s ? total : SEGW * s;  // fill start
    if (fs < fe) {
        int vstart = (fs + 3) & ~3;              // 16B-aligned fill start
        int head = (vstart < fe ? vstart : fe) - fs;
        if (tid < head) orow[fs + tid] = BLANK;
        if (vstart < fe) {
            int4* vout = reinterpret_cast<int4*>(orow + vstart);
            const int nvec = (fe - vstart) >> 2;
            const int4 z = make_int4(BLANK, BLANK, BLANK, BLANK);
            for (int i = tid; i < nvec; i += 1024) vout[i] = z;
        }
    }
    if (s == 0 && tid == 0) lens[b] = total;
}

// ---------------------------------------------------------------------------
extern "C" void kernel_launch(void* const* d_in, const int* in_sizes, int n_in,
                              void* d_out, int out_size, void* d_ws, size_t ws_size,
                              hipStream_t stream) {
    const float* emission = (const float*)d_in[0];
    int* out = (int*)d_out;                 // [B*T btokens][B lens], int32
    int* btokens = out;
    int* lens = out + (size_t)CTC_B * CTC_T;

    unsigned char* idx = (unsigned char*)d_ws;   // B*T bytes

    const int total_threads = CTC_B * CTC_T * 4; // 4 lanes per row
    ctc_argmax_kernel<<<total_threads / 256, 256, 0, stream>>>(emission, idx);
    ctc_compact_kernel<<<CTC_B * SEGS, 1024, 0, stream>>>(idx, btokens, lens);
}

// Round 13
// 19.538 us; speedup vs baseline: 1.3670x; 1.0341x over previous
//
#include <hip/hip_runtime.h>
#include <hip/hip_bf16.h>

// Problem constants (from reference setup_inputs): emission [B, T, V] float32
#define CTC_B 64
#define CTC_T 8192
#define CTC_V 32
#define BLANK 0

#define SEGS 4
#define SEGW (CTC_T / SEGS)   // 2048 output columns per block

// ---------------------------------------------------------------------------
// Kernel 1: argmax over labels. 4 lanes per (b,t) row; fmaxf tree + equality
// index scan (first-occurrence tie-break identical to jnp.argmax).
// Measured at 10.87 us marginal = 98% of the 6.3 TB/s read ceiling (R9).
// ---------------------------------------------------------------------------
__global__ __launch_bounds__(256) void ctc_argmax_kernel(
    const float* __restrict__ em, unsigned char* __restrict__ idx) {
    int tid = blockIdx.x * blockDim.x + threadIdx.x;   // 4 threads per row
    int row = tid >> 2;
    int sub = tid & 3;
    const float4* p = reinterpret_cast<const float4*>(em) + (size_t)row * 8 + sub;
    float4 a = p[0];   // covers elements 4*sub    .. 4*sub+3
    float4 b = p[4];   // covers elements 16+4*sub .. 16+4*sub+3

    // in-lane max of 8 values: v_max3-friendly tree (4 ops)
    float m0 = __builtin_fmaxf(__builtin_fmaxf(a.x, a.y), a.z);
    float m1 = __builtin_fmaxf(__builtin_fmaxf(a.w, b.x), b.y);
    float m2 = __builtin_fmaxf(b.z, b.w);
    float g  = __builtin_fmaxf(__builtin_fmaxf(m0, m1), m2);

    // group max across the 4-lane group (xor masks 1,2 stay in-group)
    g = __builtin_fmaxf(g, __shfl_xor(g, 1, 64));
    g = __builtin_fmaxf(g, __shfl_xor(g, 2, 64));

    // local first-match index in global element order (descending scan ->
    // earliest e wins); sentinel 255 if this lane has no match.
    const int e1 = sub * 4, e2 = 16 + sub * 4;
    int li = 255;
    if (b.w == g) li = e2 + 3;
    if (b.z == g) li = e2 + 2;
    if (b.y == g) li = e2 + 1;
    if (b.x == g) li = e2;
    if (a.w == g) li = e1 + 3;
    if (a.z == g) li = e1 + 2;
    if (a.y == g) li = e1 + 1;
    if (a.x == g) li = e1;

    // group min-index (at least one lane has a match)
    li = min(li, __shfl_xor(li, 1, 64));
    li = min(li, __shfl_xor(li, 2, 64));

    if (sub == 0) idx[row] = (unsigned char)li;   // 16 consecutive bytes/wave
}

// ---------------------------------------------------------------------------
// SWAR: high bit of each byte set iff that byte of x is nonzero.
// ---------------------------------------------------------------------------
__device__ __forceinline__ unsigned long long nzmask(unsigned long long x) {
    return (x | ((x & 0x7f7f7f7f7f7f7f7fULL) + 0x7f7f7f7f7f7f7f7fULL))
           & 0x8080808080808080ULL;
}

// ---------------------------------------------------------------------------
// Kernel 2 (fused colkeep + compact), R13: LDS-staged compaction.
// 256 blocks (b = blk & 63, s = blk >> 6), 1024 threads:
//   - all threads: full row-b keep-mask + block scan (redundant x4, cheap);
//   - all threads: byte-scatter kept tokens into tok[8192] in LDS;
//   - barrier; all threads emit segment [2048s, 2048(s+1)) as coalesced
//     int2 stores, selecting BLANK past `total` (scatter+fill unified,
//     branchless, 8 B/lane).
// ---------------------------------------------------------------------------
__global__ __launch_bounds__(1024) void ctc_compact_kernel(
    const unsigned char* __restrict__ idx,
    int* __restrict__ btokens, int* __restrict__ lens) {
    const int blk = blockIdx.x;
    const int b   = blk & 63;
    const int s   = blk >> 6;
    const int tid = threadIdx.x;
    const int t8  = tid * 8;                     // first column this thread owns
    const unsigned char* row = idx + (size_t)b * CTC_T;
    int* orow = btokens + (size_t)b * CTC_T;

    __shared__ int s_wsum[16];
    __shared__ unsigned char tok[CTC_T];         // compacted row (8 KB)
    const int lane = tid & 63;
    const int wid  = tid >> 6;

    // --- load own 8 values + boundary byte, and dedup rows 0,1 ---
    const unsigned long long xv = *reinterpret_cast<const unsigned long long*>(row + t8);
    const unsigned char* r0 = idx;               // batch row 0
    const unsigned char* r1 = idx + CTC_T;       // batch row 1
    unsigned long long x0 = *reinterpret_cast<const unsigned long long*>(r0 + t8);
    unsigned long long x1 = *reinterpret_cast<const unsigned long long*>(r1 + t8);
    unsigned char p0 = (t8 == 0) ? (unsigned char)0 : r0[t8 - 1];
    unsigned char p1 = (t8 == 0) ? (unsigned char)0 : r1[t8 - 1];

    // colkeep high-bit mask: byte j <-> column t8+j ; prev column = byte j-1
    unsigned long long hk = nzmask(x0 ^ ((x0 << 8) | (unsigned long long)p0))
                          | nzmask(x1 ^ ((x1 << 8) | (unsigned long long)p1));
    if (t8 == 0) hk |= 0x80ULL;                  // col_keep[0] = 1 always

    unsigned long long und = ~hk & 0x8080808080808080ULL;
    for (int bb = 2; bb < CTC_B && und; ++bb) {
        const unsigned char* rb = idx + (size_t)bb * CTC_T;
        unsigned long long xb = *reinterpret_cast<const unsigned long long*>(rb + t8);
        unsigned char pb = (t8 == 0) ? (unsigned char)0 : rb[t8 - 1];
        hk |= nzmask(xb ^ ((xb << 8) | (unsigned long long)pb));
        und = ~hk & 0x8080808080808080ULL;
    }

    // keep = col_keep & (value != BLANK)   (BLANK==0 -> nonzero byte)
    const unsigned long long keep_hi = hk & nzmask(xv);
    const int c = __popcll(keep_hi);

    // --- block exclusive scan of per-thread counts (identical in all 4
    //     blocks of row b) ---
    int scan = c;
#pragma unroll
    for (int m = 1; m < 64; m <<= 1) {
        int o = __shfl_up(scan, m, 64);
        if (lane >= m) scan += o;
    }
    if (lane == 63) s_wsum[wid] = scan;          // wave total (inclusive of last)
    __syncthreads();

    int woff = 0, total = 0;
#pragma unroll
    for (int w = 0; w < 16; ++w) {
        int x = s_wsum[w];
        if (w < wid) woff += x;
        total += x;
    }
    int pos = woff + (scan - c);                 // global exclusive prefix

    // --- byte-scatter kept tokens into LDS (covers tok[0..total)) ---
#pragma unroll
    for (int j = 0; j < 8; ++j) {
        if (keep_hi & (0x80ULL << (8 * j))) {
            tok[pos++] = (unsigned char)((xv >> (8 * j)) & 0xffULL);
        }
    }
    __syncthreads();

    // --- emit this block's output segment: branchless coalesced int2 ---
    const int base = SEGW * s + 2 * tid;
    int2 o;
    o.x = (base     < total) ? (int)tok[base]     : BLANK;
    o.y = (base + 1 < total) ? (int)tok[base + 1] : BLANK;
    *reinterpret_cast<int2*>(orow + base) = o;

    if (s == 0 && tid == 0) lens[b] = total;
}

// ---------------------------------------------------------------------------
extern "C" void kernel_launch(void* const* d_in, const int* in_sizes, int n_in,
                              void* d_out, int out_size, void* d_ws, size_t ws_size,
                              hipStream_t stream) {
    const float* emission = (const float*)d_in[0];
    int* out = (int*)d_out;                 // [B*T btokens][B lens], int32
    int* btokens = out;
    int* lens = out + (size_t)CTC_B * CTC_T;

    unsigned char* idx = (unsigned char*)d_ws;   // B*T bytes

    const int total_threads = CTC_B * CTC_T * 4; // 4 lanes per row
    ctc_argmax_kernel<<<total_threads / 256, 256, 0, stream>>>(emission, idx);
    ctc_compact_kernel<<<CTC_B * SEGS, 1024, 0, stream>>>(idx, btokens, lens);
}